// Round 2
// baseline (25604.529 us; speedup 1.0000x reference)
//
#include <hip/hip_runtime.h>

// GRU: B=64, T=512, IN=256, H=1024, OUT=10.
// Persistent cooperative-style kernel: weights resident in VGPRs (fp16 hi/lo
// split -> ~f32 accuracy with MFMA), one device-scope barrier per timestep.

#define TT  512
#define BB  64
#define KIN 256
#define HH  1024

typedef _Float16 half8  __attribute__((ext_vector_type(8)));
typedef _Float16 half4v __attribute__((ext_vector_type(4)));
typedef float    float4v __attribute__((ext_vector_type(4)));

// ---- workspace layout (bytes) ----
#define XF_OFF   0u                     // fp16 x, [T][B][K] = 16,777,216 B
#define HB0_OFF  16777216u              // fp16 h ping  [B][H] = 131,072 B
#define HB1_OFF  16908288u              // fp16 h pong
#define HF32_OFF 17039360u              // f32 h_last [B][H] = 262,144 B
#define CNT_OFF  17301504u              // barrier counters (8 KB)

// x[b][t][k] f32 -> xf[t][b][k] fp16
__global__ __launch_bounds__(256) void k_prep_x(const float* __restrict__ x,
                                                _Float16* __restrict__ xf) {
    const int t  = blockIdx.x;
    const int tid = threadIdx.x;
    const int k4 = (tid & 63) << 2;
    const int bw = tid >> 6;
#pragma unroll
    for (int bi = 0; bi < 16; ++bi) {
        const int b = (bw << 4) + bi;
        float4v v = *(const float4v*)(x + ((size_t)b * TT + t) * KIN + k4);
        half4v h;
        h[0] = (_Float16)v[0]; h[1] = (_Float16)v[1];
        h[2] = (_Float16)v[2]; h[3] = (_Float16)v[3];
        *(half4v*)(xf + ((size_t)t * BB + b) * KIN + k4) = h;
    }
}

__device__ __forceinline__ void split8(const float* __restrict__ p,
                                       half8& hi, half8& lo) {
#pragma unroll
    for (int i = 0; i < 8; ++i) {
        float v = p[i];
        _Float16 h = (_Float16)v;
        hi[i] = h;
        lo[i] = (_Float16)(v - (float)h);
    }
}

// Device-scope barrier: release my block's writes, arrive, spin, acquire.
__device__ __forceinline__ void grid_barrier(unsigned* cnt, unsigned target) {
    __threadfence();                 // release (wb L2) before arrival
    __syncthreads();
    if (threadIdx.x == 0) {
        __hip_atomic_fetch_add(cnt, 1u, __ATOMIC_ACQ_REL, __HIP_MEMORY_SCOPE_AGENT);
        while (__hip_atomic_load(cnt, __ATOMIC_ACQUIRE, __HIP_MEMORY_SCOPE_AGENT) < target)
            __builtin_amdgcn_s_sleep(2);
    }
    __syncthreads();
    __threadfence();                 // acquire (inv caches) before reading peers' data
}

__global__ __launch_bounds__(256, 1) void k_gru_persist(
    const _Float16* __restrict__ xf, const float* __restrict__ Wx,
    const float* __restrict__ bx, const float* __restrict__ Wh,
    const float* __restrict__ bh, const float* __restrict__ Wfc,
    const float* __restrict__ bfc, _Float16* __restrict__ hb0,
    _Float16* __restrict__ hb1, float* __restrict__ hf32,
    unsigned* __restrict__ cnt, float* __restrict__ out)
{
    __shared__ char smem[32768 + 8192 + 17408];
    _Float16* h_lds = (_Float16*)smem;            // [16 b][1024 k] swizzled
    _Float16* x_lds = (_Float16*)(smem + 32768);  // [16 b][256 k] swizzled
    float*    red   = (float*)(smem + 40960);     // [4 w][4 comp][16 j][17]

    const int tid  = threadIdx.x;
    const int lane = tid & 63;
    const int wv   = tid >> 6;          // wave = K-slice
    const int jsl  = blockIdx.x & 63;   // j-slice   (same-jsl btiles land on same XCD slot? not needed)
    const int btl  = blockIdx.x >> 6;   // batch tile; h-communication is btl-private
    const int j0   = jsl << 4;
    const int b0   = btl << 4;

    const int arow = lane & 15;         // MFMA A row / B col / D col
    const int kg   = lane >> 4;         // MFMA k-group
    const int swz  = (arow & 7) << 4;

    // ---- prologue: resident weights as fp16 hi/lo MFMA fragments ----
    half8 ahh[3][8], ahl[3][8], axh[3][2], axl[3][2];
#pragma unroll
    for (int g = 0; g < 3; ++g) {
#pragma unroll
        for (int s = 0; s < 8; ++s) {
            const float* p = Wh + (size_t)((g << 10) + j0 + arow) * HH
                               + ((wv << 8) + (s << 5) + (kg << 3));
            split8(p, ahh[g][s], ahl[g][s]);
        }
#pragma unroll
        for (int s = 0; s < 2; ++s) {
            const float* p = Wx + (size_t)((g << 10) + j0 + arow) * KIN
                               + ((wv << 6) + (s << 5) + (kg << 3));
            split8(p, axh[g][s], axl[g][s]);
        }
    }

    const int jh  = tid >> 4;    // 0..15 -> owns gate element (j0+jh, b0+bhi)
    const int bhi = tid & 15;
    const int j   = j0 + jh;
    const float bxr = bx[j], bxi = bx[HH + j], bxn = bx[2 * HH + j];
    const float bhr = bh[j], bhi_ = bh[HH + j], bhn = bh[2 * HH + j];
    float hprev = 0.f;

    unsigned* cntb = cnt + (btl << 6);   // per-batch-tile barrier (64 blocks)
    unsigned* cntf = cnt + 1024;         // final global barrier

    for (int t = 0; t < TT; ++t) {
        const _Float16* hs = (t & 1) ? hb1 : hb0;
        _Float16*       hd = (t & 1) ? hb0 : hb1;
        const _Float16* xs = xf + (size_t)t * (BB * KIN);

        // stage h rows b0..b0+15 (32 KB) and x rows (8 KB), XOR-swizzled
#pragma unroll
        for (int i = 0; i < 8; ++i) {
            int c = tid + (i << 8);
            int br = c >> 7, kc = c & 127;
            uint4 v = *(const uint4*)(hs + (size_t)(b0 + br) * HH + (kc << 3));
            *(uint4*)((char*)h_lds + (br << 11) + ((kc << 4) ^ ((br & 7) << 4))) = v;
        }
#pragma unroll
        for (int i = 0; i < 2; ++i) {
            int c = tid + (i << 8);
            int br = c >> 5, kc = c & 31;
            uint4 v = *(const uint4*)(xs + (size_t)(b0 + br) * KIN + (kc << 3));
            *(uint4*)((char*)x_lds + (br << 9) + ((kc << 4) ^ ((br & 7) << 4))) = v;
        }
        __syncthreads();

        float4v ar = {0,0,0,0}, ai = {0,0,0,0}, anx = {0,0,0,0}, anh = {0,0,0,0};
#pragma unroll
        for (int s = 0; s < 8; ++s) {
            half8 bf = *(const half8*)((char*)h_lds + (arow << 11)
                        + (((wv << 9) + (s << 6) + (kg << 4)) ^ swz));
            ar  = __builtin_amdgcn_mfma_f32_16x16x32_f16(ahh[0][s], bf, ar, 0, 0, 0);
            ar  = __builtin_amdgcn_mfma_f32_16x16x32_f16(ahl[0][s], bf, ar, 0, 0, 0);
            ai  = __builtin_amdgcn_mfma_f32_16x16x32_f16(ahh[1][s], bf, ai, 0, 0, 0);
            ai  = __builtin_amdgcn_mfma_f32_16x16x32_f16(ahl[1][s], bf, ai, 0, 0, 0);
            anh = __builtin_amdgcn_mfma_f32_16x16x32_f16(ahh[2][s], bf, anh, 0, 0, 0);
            anh = __builtin_amdgcn_mfma_f32_16x16x32_f16(ahl[2][s], bf, anh, 0, 0, 0);
        }
#pragma unroll
        for (int s = 0; s < 2; ++s) {
            half8 bf = *(const half8*)((char*)x_lds + (arow << 9)
                        + (((wv << 7) + (s << 6) + (kg << 4)) ^ swz));
            ar  = __builtin_amdgcn_mfma_f32_16x16x32_f16(axh[0][s], bf, ar, 0, 0, 0);
            ar  = __builtin_amdgcn_mfma_f32_16x16x32_f16(axl[0][s], bf, ar, 0, 0, 0);
            ai  = __builtin_amdgcn_mfma_f32_16x16x32_f16(axh[1][s], bf, ai, 0, 0, 0);
            ai  = __builtin_amdgcn_mfma_f32_16x16x32_f16(axl[1][s], bf, ai, 0, 0, 0);
            anx = __builtin_amdgcn_mfma_f32_16x16x32_f16(axh[2][s], bf, anx, 0, 0, 0);
            anx = __builtin_amdgcn_mfma_f32_16x16x32_f16(axl[2][s], bf, anx, 0, 0, 0);
        }

        // cross-wave K reduction through LDS (rows padded to 17 floats)
#pragma unroll
        for (int r = 0; r < 4; ++r) {
            int row = (kg << 2) + r;
            red[(((wv << 2) + 0) * 16 + row) * 17 + arow] = ar[r];
            red[(((wv << 2) + 1) * 16 + row) * 17 + arow] = ai[r];
            red[(((wv << 2) + 2) * 16 + row) * 17 + arow] = anx[r];
            red[(((wv << 2) + 3) * 16 + row) * 17 + arow] = anh[r];
        }
        __syncthreads();

        float sr = 0.f, si = 0.f, sx = 0.f, sh = 0.f;
#pragma unroll
        for (int w2 = 0; w2 < 4; ++w2) {
            sr += red[(((w2 << 2) + 0) * 16 + jh) * 17 + bhi];
            si += red[(((w2 << 2) + 1) * 16 + jh) * 17 + bhi];
            sx += red[(((w2 << 2) + 2) * 16 + jh) * 17 + bhi];
            sh += red[(((w2 << 2) + 3) * 16 + jh) * 17 + bhi];
        }
        float rg = 1.f / (1.f + __expf(-(sr + bxr + bhr)));
        float ig = 1.f / (1.f + __expf(-(si + bxi + bhi_)));
        float ng = tanhf(sx + bxn + rg * (sh + bhn));
        hprev = ng + ig * (hprev - ng);
        hd[(size_t)(b0 + bhi) * HH + j] = (_Float16)hprev;

        grid_barrier(cntb, 64u * (unsigned)(t + 1));
    }

    // publish final h (f32), sync everyone, then 64 blocks do the tiny FC
    hf32[(size_t)(b0 + bhi) * HH + j] = hprev;
    grid_barrier(cntf, 256u);

    if (blockIdx.x < 64) {
        const int b = blockIdx.x;
        const float* hbp = hf32 + (size_t)b * HH;
        float4v h4 = *(const float4v*)(hbp + (tid << 2));
        float partial[10];
#pragma unroll
        for (int o = 0; o < 10; ++o) {
            float4v w4 = *(const float4v*)(Wfc + (size_t)o * HH + (tid << 2));
            partial[o] = h4[0]*w4[0] + h4[1]*w4[1] + h4[2]*w4[2] + h4[3]*w4[3];
        }
        float* r = (float*)smem;   // [10][256]
#pragma unroll
        for (int o = 0; o < 10; ++o) r[o * 256 + tid] = partial[o];
        __syncthreads();
        for (int off = 128; off >= 1; off >>= 1) {
            if (tid < off) {
#pragma unroll
                for (int o = 0; o < 10; ++o)
                    r[o * 256 + tid] += r[o * 256 + tid + off];
            }
            __syncthreads();
        }
        if (tid < 10) out[b * 10 + tid] = r[tid * 256] + bfc[tid];
    }
}

extern "C" void kernel_launch(void* const* d_in, const int* in_sizes, int n_in,
                              void* d_out, int out_size, void* d_ws, size_t ws_size,
                              hipStream_t stream) {
    (void)in_sizes; (void)n_in; (void)out_size; (void)ws_size;
    const float* x   = (const float*)d_in[0];
    const float* Wx  = (const float*)d_in[1];
    const float* bx  = (const float*)d_in[2];
    const float* Wh  = (const float*)d_in[3];
    const float* bh  = (const float*)d_in[4];
    const float* Wfc = (const float*)d_in[5];
    const float* bfc = (const float*)d_in[6];
    float* out = (float*)d_out;

    char* ws = (char*)d_ws;
    _Float16* xf   = (_Float16*)(ws + XF_OFF);
    _Float16* hb0  = (_Float16*)(ws + HB0_OFF);
    _Float16* hb1  = (_Float16*)(ws + HB1_OFF);
    float*    hf32 = (float*)(ws + HF32_OFF);
    unsigned* cnt  = (unsigned*)(ws + CNT_OFF);

    // zero h ping-pong buffers (t=0 reads zeros) and barrier counters
    hipMemsetAsync(ws + HB0_OFF, 0, 262144, stream);
    hipMemsetAsync(ws + CNT_OFF, 0, 8192, stream);

    k_prep_x<<<512, 256, 0, stream>>>(x, xf);
    k_gru_persist<<<256, 256, 0, stream>>>(xf, Wx, bx, Wh, bh, Wfc, bfc,
                                           hb0, hb1, hf32, cnt, out);
}

// Round 3
// 4437.408 us; speedup vs baseline: 5.7702x; 5.7702x over previous
//
#include <hip/hip_runtime.h>

// GRU: B=64, T=512, IN=256, H=1024, OUT=10.
// Persistent kernel, weights resident in VGPRs (fp16 hi/lo -> ~f32 accuracy),
// one flag-array barrier per timestep using RELAXED agent-scope (sc1)
// atomics only -- no __threadfence / acquire fences (those emit whole-L2
// buffer_wbl2/buffer_inv on gfx950 and were the round-1 disaster).

#define TT  512
#define BB  64
#define KIN 256
#define HH  1024

typedef _Float16 half8  __attribute__((ext_vector_type(8)));
typedef _Float16 half4v __attribute__((ext_vector_type(4)));
typedef float    float4v __attribute__((ext_vector_type(4)));

// ---- workspace layout (bytes) ----
#define XF_OFF   0u                     // fp16 x, [T][B][K] = 16,777,216 B
#define HB0_OFF  16777216u              // fp16 h ping  [B][H] = 131,072 B
#define HB1_OFF  16908288u              // fp16 h pong
#define HF32_OFF 17039360u              // f32 h_last [B][H] = 262,144 B
#define FLG_OFF  17301504u              // flags[4][64] u32 (+ pad) = 8 KB

// x[b][t][k] f32 -> xf[t][b][k] fp16
__global__ __launch_bounds__(256) void k_prep_x(const float* __restrict__ x,
                                                _Float16* __restrict__ xf) {
    const int t  = blockIdx.x;
    const int tid = threadIdx.x;
    const int k4 = (tid & 63) << 2;
    const int bw = tid >> 6;
#pragma unroll
    for (int bi = 0; bi < 16; ++bi) {
        const int b = (bw << 4) + bi;
        float4v v = *(const float4v*)(x + ((size_t)b * TT + t) * KIN + k4);
        half4v h;
        h[0] = (_Float16)v[0]; h[1] = (_Float16)v[1];
        h[2] = (_Float16)v[2]; h[3] = (_Float16)v[3];
        *(half4v*)(xf + ((size_t)t * BB + b) * KIN + k4) = h;
    }
}

__device__ __forceinline__ void split8(const float* __restrict__ p,
                                       half8& hi, half8& lo) {
#pragma unroll
    for (int i = 0; i < 8; ++i) {
        float v = p[i];
        _Float16 h = (_Float16)v;
        hi[i] = h;
        lo[i] = (_Float16)(v - (float)h);
    }
}

__device__ __forceinline__ unsigned ld_sc1(const unsigned* p) {
    return __hip_atomic_load((unsigned*)p, __ATOMIC_RELAXED, __HIP_MEMORY_SCOPE_AGENT);
}
__device__ __forceinline__ unsigned long long ld_sc1_u64(const void* p) {
    return __hip_atomic_load((unsigned long long*)p, __ATOMIC_RELAXED, __HIP_MEMORY_SCOPE_AGENT);
}

// Flag barrier for a 64-block group. Producer side: callers' sc1 data stores
// are drained (vmcnt 0) in EVERY thread, then block publishes flag=tgt (sc1).
// Consumer side: wave 0's 64 lanes each spin on one flag with relaxed sc1
// loads (single coalesced 256B load per poll; no cache invalidates).
__device__ __forceinline__ void step_barrier(unsigned* flags, int jsl, unsigned tgt) {
    asm volatile("s_waitcnt vmcnt(0)" ::: "memory");
    __syncthreads();
    if (threadIdx.x == 0)
        __hip_atomic_store(&flags[jsl], tgt, __ATOMIC_RELAXED, __HIP_MEMORY_SCOPE_AGENT);
    if (threadIdx.x < 64) {
        while (ld_sc1(&flags[threadIdx.x]) < tgt)
            __builtin_amdgcn_s_sleep(1);
    }
    __syncthreads();
}

__global__ __launch_bounds__(256, 1) void k_gru_persist(
    const _Float16* __restrict__ xf, const float* __restrict__ Wx,
    const float* __restrict__ bx, const float* __restrict__ Wh,
    const float* __restrict__ bh, const float* __restrict__ Wfc,
    const float* __restrict__ bfc, _Float16* __restrict__ hb0,
    _Float16* __restrict__ hb1, float* __restrict__ hf32,
    unsigned* __restrict__ flags, float* __restrict__ out)
{
    __shared__ char smem[32768 + 8192 + 17408];
    _Float16* h_lds = (_Float16*)smem;            // [16 b][1024 k] swizzled
    _Float16* x_lds = (_Float16*)(smem + 32768);  // [16 b][256 k] swizzled
    float*    red   = (float*)(smem + 40960);     // [4 w][4 comp][16 j][17]

    const int tid  = threadIdx.x;
    const int lane = tid & 63;
    const int wv   = tid >> 6;          // wave = K-slice
    const int jsl  = blockIdx.x & 63;   // j-slice
    const int btl  = blockIdx.x >> 6;   // batch tile (h-communication is btl-private)
    const int j0   = jsl << 4;
    const int b0   = btl << 4;

    const int arow = lane & 15;         // MFMA A row (j) / B col (b) / D col (b)
    const int kg   = lane >> 4;         // MFMA k-group
    const int swz  = (arow & 7) << 4;

    // ---- prologue: resident weights as fp16 hi/lo MFMA fragments ----
    half8 ahh[3][8], ahl[3][8], axh[3][2], axl[3][2];
#pragma unroll
    for (int g = 0; g < 3; ++g) {
#pragma unroll
        for (int s = 0; s < 8; ++s) {
            const float* p = Wh + (size_t)((g << 10) + j0 + arow) * HH
                               + ((wv << 8) + (s << 5) + (kg << 3));
            split8(p, ahh[g][s], ahl[g][s]);
        }
#pragma unroll
        for (int s = 0; s < 2; ++s) {
            const float* p = Wx + (size_t)((g << 10) + j0 + arow) * KIN
                               + ((wv << 6) + (s << 5) + (kg << 3));
            split8(p, axh[g][s], axl[g][s]);
        }
    }

    // gate-element ownership: jh = tid&15 (consecutive tid -> consecutive j,
    // so h publishes coalesce), bhi = tid>>4
    const int jh  = tid & 15;
    const int bhi = tid >> 4;
    const int j   = j0 + jh;
    const float bxr = bx[j], bxi = bx[HH + j], bxn = bx[2 * HH + j];
    const float bhr = bh[j], bhi_ = bh[HH + j], bhn = bh[2 * HH + j];
    float hprev = 0.f;

    unsigned* flg = flags + (btl << 6);   // per-batch-tile flag group

    for (int t = 0; t < TT; ++t) {
        const _Float16* hs = (t & 1) ? hb1 : hb0;
        _Float16*       hd = (t & 1) ? hb0 : hb1;
        const _Float16* xs = xf + (size_t)t * (BB * KIN);

        // stage h rows b0..b0+15 (32 KB) via sc1 8B loads (bypass stale L2),
        // XOR-swizzled into LDS; x rows (8 KB) via plain 16B loads.
#pragma unroll
        for (int i = 0; i < 16; ++i) {
            int c = tid + (i << 8);
            int br = c >> 8, kc = c & 255;
            unsigned long long v =
                ld_sc1_u64(hs + (size_t)(b0 + br) * HH + (kc << 2));
            *(unsigned long long*)((char*)h_lds + (br << 11)
                + ((kc << 3) ^ ((br & 7) << 4))) = v;
        }
#pragma unroll
        for (int i = 0; i < 2; ++i) {
            int c = tid + (i << 8);
            int br = c >> 5, kc = c & 31;
            uint4 v = *(const uint4*)(xs + (size_t)(b0 + br) * KIN + (kc << 3));
            *(uint4*)((char*)x_lds + (br << 9) + ((kc << 4) ^ ((br & 7) << 4))) = v;
        }
        __syncthreads();

        float4v ar = {0,0,0,0}, ai = {0,0,0,0}, anx = {0,0,0,0}, anh = {0,0,0,0};
#pragma unroll
        for (int s = 0; s < 8; ++s) {
            half8 bf = *(const half8*)((char*)h_lds + (arow << 11)
                        + (((wv << 9) + (s << 6) + (kg << 4)) ^ swz));
            ar  = __builtin_amdgcn_mfma_f32_16x16x32_f16(ahh[0][s], bf, ar, 0, 0, 0);
            ar  = __builtin_amdgcn_mfma_f32_16x16x32_f16(ahl[0][s], bf, ar, 0, 0, 0);
            ai  = __builtin_amdgcn_mfma_f32_16x16x32_f16(ahh[1][s], bf, ai, 0, 0, 0);
            ai  = __builtin_amdgcn_mfma_f32_16x16x32_f16(ahl[1][s], bf, ai, 0, 0, 0);
            anh = __builtin_amdgcn_mfma_f32_16x16x32_f16(ahh[2][s], bf, anh, 0, 0, 0);
            anh = __builtin_amdgcn_mfma_f32_16x16x32_f16(ahl[2][s], bf, anh, 0, 0, 0);
        }
#pragma unroll
        for (int s = 0; s < 2; ++s) {
            half8 bf = *(const half8*)((char*)x_lds + (arow << 9)
                        + (((wv << 7) + (s << 6) + (kg << 4)) ^ swz));
            ar  = __builtin_amdgcn_mfma_f32_16x16x32_f16(axh[0][s], bf, ar, 0, 0, 0);
            ar  = __builtin_amdgcn_mfma_f32_16x16x32_f16(axl[0][s], bf, ar, 0, 0, 0);
            ai  = __builtin_amdgcn_mfma_f32_16x16x32_f16(axh[1][s], bf, ai, 0, 0, 0);
            ai  = __builtin_amdgcn_mfma_f32_16x16x32_f16(axl[1][s], bf, ai, 0, 0, 0);
            anx = __builtin_amdgcn_mfma_f32_16x16x32_f16(axh[2][s], bf, anx, 0, 0, 0);
            anx = __builtin_amdgcn_mfma_f32_16x16x32_f16(axl[2][s], bf, anx, 0, 0, 0);
        }

        // cross-wave K reduction through LDS (rows padded to 17 floats)
#pragma unroll
        for (int r = 0; r < 4; ++r) {
            int row = (kg << 2) + r;            // j offset in tile
            red[(((wv << 2) + 0) * 16 + row) * 17 + arow] = ar[r];
            red[(((wv << 2) + 1) * 16 + row) * 17 + arow] = ai[r];
            red[(((wv << 2) + 2) * 16 + row) * 17 + arow] = anx[r];
            red[(((wv << 2) + 3) * 16 + row) * 17 + arow] = anh[r];
        }
        __syncthreads();

        float sr = 0.f, si = 0.f, sx = 0.f, sh = 0.f;
#pragma unroll
        for (int w2 = 0; w2 < 4; ++w2) {
            sr += red[(((w2 << 2) + 0) * 16 + jh) * 17 + bhi];
            si += red[(((w2 << 2) + 1) * 16 + jh) * 17 + bhi];
            sx += red[(((w2 << 2) + 2) * 16 + jh) * 17 + bhi];
            sh += red[(((w2 << 2) + 3) * 16 + jh) * 17 + bhi];
        }
        float rg = 1.f / (1.f + __expf(-(sr + bxr + bhr)));
        float ig = 1.f / (1.f + __expf(-(si + bxi + bhi_)));
        float ng = tanhf(sx + bxn + rg * (sh + bhn));
        hprev = ng + ig * (hprev - ng);

        // publish h: pair (jh even, jh+1) into one 4B sc1 store
        unsigned short myb;
        { union { _Float16 f; unsigned short u; } cv; cv.f = (_Float16)hprev; myb = cv.u; }
        unsigned other = (unsigned)__shfl_xor((int)(unsigned)myb, 1, 64) & 0xffffu;
        if ((jh & 1) == 0) {
            unsigned word = (unsigned)myb | (other << 16);
            __hip_atomic_store((unsigned*)&hd[(size_t)(b0 + bhi) * HH + j], word,
                               __ATOMIC_RELAXED, __HIP_MEMORY_SCOPE_AGENT);
        }

        step_barrier(flg, jsl, (unsigned)(t + 1));
    }

    // publish final h (f32, sc1), then global flag barrier, then 64-block FC
    __hip_atomic_store(&hf32[(size_t)(b0 + bhi) * HH + j], hprev,
                       __ATOMIC_RELAXED, __HIP_MEMORY_SCOPE_AGENT);
    asm volatile("s_waitcnt vmcnt(0)" ::: "memory");
    __syncthreads();
    if (tid == 0)
        __hip_atomic_store(&flags[(btl << 6) + jsl], (unsigned)(TT + 1),
                           __ATOMIC_RELAXED, __HIP_MEMORY_SCOPE_AGENT);

    if (blockIdx.x < 64) {
        if (tid < 64) {
            const unsigned tgt = (unsigned)(TT + 1);
            for (;;) {
                unsigned a0 = ld_sc1(&flags[tid]);
                unsigned a1 = ld_sc1(&flags[64 + tid]);
                unsigned a2 = ld_sc1(&flags[128 + tid]);
                unsigned a3 = ld_sc1(&flags[192 + tid]);
                unsigned mn = min(min(a0, a1), min(a2, a3));
                if (__all(mn >= tgt)) break;
                __builtin_amdgcn_s_sleep(2);
            }
        }
        __syncthreads();

        const int b = blockIdx.x;
        const float* hbp = hf32 + (size_t)b * HH;
        float hv[4];
#pragma unroll
        for (int q = 0; q < 4; ++q)
            hv[q] = __hip_atomic_load((float*)(hbp + (tid << 2) + q),
                                      __ATOMIC_RELAXED, __HIP_MEMORY_SCOPE_AGENT);
        float partial[10];
#pragma unroll
        for (int o = 0; o < 10; ++o) {
            float4v w4 = *(const float4v*)(Wfc + (size_t)o * HH + (tid << 2));
            partial[o] = hv[0]*w4[0] + hv[1]*w4[1] + hv[2]*w4[2] + hv[3]*w4[3];
        }
        float* r = (float*)smem;   // [10][256]
#pragma unroll
        for (int o = 0; o < 10; ++o) r[o * 256 + tid] = partial[o];
        __syncthreads();
        for (int off = 128; off >= 1; off >>= 1) {
            if (tid < off) {
#pragma unroll
                for (int o = 0; o < 10; ++o)
                    r[o * 256 + tid] += r[o * 256 + tid + off];
            }
            __syncthreads();
        }
        if (tid < 10) out[b * 10 + tid] = r[tid * 256] + bfc[tid];
    }
}

extern "C" void kernel_launch(void* const* d_in, const int* in_sizes, int n_in,
                              void* d_out, int out_size, void* d_ws, size_t ws_size,
                              hipStream_t stream) {
    (void)in_sizes; (void)n_in; (void)out_size; (void)ws_size;
    const float* x   = (const float*)d_in[0];
    const float* Wx  = (const float*)d_in[1];
    const float* bx  = (const float*)d_in[2];
    const float* Wh  = (const float*)d_in[3];
    const float* bh  = (const float*)d_in[4];
    const float* Wfc = (const float*)d_in[5];
    const float* bfc = (const float*)d_in[6];
    float* out = (float*)d_out;

    char* ws = (char*)d_ws;
    _Float16* xf   = (_Float16*)(ws + XF_OFF);
    _Float16* hb0  = (_Float16*)(ws + HB0_OFF);
    _Float16* hb1  = (_Float16*)(ws + HB1_OFF);
    float*    hf32 = (float*)(ws + HF32_OFF);
    unsigned* flags = (unsigned*)(ws + FLG_OFF);

    // zero h ping-pong buffers (t=0 reads zeros) and barrier flags
    hipMemsetAsync(ws + HB0_OFF, 0, 262144, stream);
    hipMemsetAsync(ws + FLG_OFF, 0, 8192, stream);

    k_prep_x<<<512, 256, 0, stream>>>(x, xf);
    k_gru_persist<<<256, 256, 0, stream>>>(xf, Wx, bx, Wh, bh, Wfc, bfc,
                                           hb0, hb1, hf32, flags, out);
}

// Round 5
// 2951.540 us; speedup vs baseline: 8.6750x; 1.5034x over previous
//
#include <hip/hip_runtime.h>

// GRU: B=64, T=512, IN=256, H=1024, OUT=10.
// Persistent kernel, 256 blocks (proven co-resident config), weights resident
// as fp16 hi/lo MFMA fragments (~f32 accuracy). NO per-step flag barrier:
// h is published as u32 {epoch:16 | fp16 h:16}; consumers poll the data
// itself (data-as-flag). Ping-pong + single-writer + publish-after-read
// makes this a complete synchronization (see round-4 analysis).

#define TT  512
#define BB  64
#define KIN 256
#define HH  1024

typedef _Float16 half8   __attribute__((ext_vector_type(8)));
typedef _Float16 half4v  __attribute__((ext_vector_type(4)));
typedef float    float4v __attribute__((ext_vector_type(4)));
typedef unsigned uint4v  __attribute__((ext_vector_type(4)));

// ---- workspace layout (bytes) ----
#define XF_OFF   0u           // fp16 x [T][B][K] = 16,777,216
#define HB0_OFF  16777216u    // u32 {tag|h} ping [B][H] = 262,144
#define HB1_OFF  17039360u    // u32 {tag|h} pong [B][H] = 262,144

// x[b][t][k] f32 -> xf[t][b][k] fp16
__global__ __launch_bounds__(256) void k_prep_x(const float* __restrict__ x,
                                                _Float16* __restrict__ xf) {
    const int t   = blockIdx.x;
    const int tid = threadIdx.x;
    const int k4  = (tid & 63) << 2;
    const int bw  = tid >> 6;
#pragma unroll
    for (int bi = 0; bi < 16; ++bi) {
        const int b = (bw << 4) + bi;
        float4v v = *(const float4v*)(x + ((size_t)b * TT + t) * KIN + k4);
        half4v h;
        h[0] = (_Float16)v[0]; h[1] = (_Float16)v[1];
        h[2] = (_Float16)v[2]; h[3] = (_Float16)v[3];
        *(half4v*)(xf + ((size_t)t * BB + b) * KIN + k4) = h;
    }
}

__device__ __forceinline__ void split8(const float* __restrict__ p,
                                       half8& hi, half8& lo) {
#pragma unroll
    for (int i = 0; i < 8; ++i) {
        float v = p[i];
        _Float16 h = (_Float16)v;
        hi[i] = h;
        lo[i] = (_Float16)(v - (float)h);
    }
}

__device__ __forceinline__ unsigned long long ld_ag64(const void* p) {
    return __hip_atomic_load((const unsigned long long*)p, __ATOMIC_RELAXED,
                             __HIP_MEMORY_SCOPE_AGENT);
}
__device__ __forceinline__ void st_ag64(void* p, unsigned long long v) {
    __hip_atomic_store((unsigned long long*)p, v, __ATOMIC_RELAXED,
                       __HIP_MEMORY_SCOPE_AGENT);
}

__global__ __launch_bounds__(256, 1) void k_gru_persist(
    const _Float16* __restrict__ xf, const float* __restrict__ Wx,
    const float* __restrict__ bx, const float* __restrict__ Wh,
    const float* __restrict__ bh, const float* __restrict__ Wfc,
    const float* __restrict__ bfc, unsigned* __restrict__ hb0,
    unsigned* __restrict__ hb1, float* __restrict__ out)
{
    __shared__ char smem[58368];
    _Float16* h_lds = (_Float16*)smem;             // [16 b][1024 k] swz, 32KB
    _Float16* x_lds = (_Float16*)(smem + 32768);   // [16 b][256 k] swz, 8KB
    float*    red   = (float*)(smem + 40960);      // [4 w][4 c][16 j][17]

    const int tid  = threadIdx.x;
    const int lane = tid & 63;
    const int wv   = tid >> 6;          // wave = K-slice
    const int jsl  = blockIdx.x & 63;   // j-slice
    const int btl  = blockIdx.x >> 6;   // batch tile (communication is btl-private)
    const int j0   = jsl << 4;
    const int b0   = btl << 4;

    const int arow = lane & 15;         // MFMA A row (j) / D col (b)
    const int kg   = lane >> 4;         // MFMA k-group
    const int swz  = (arow & 7) << 4;

    // ---- resident weights: fp16 hi/lo MFMA fragments (AGPR-backed) ----
    half8 ahh[3][8], ahl[3][8], axh[3][2], axl[3][2];
#pragma unroll
    for (int g = 0; g < 3; ++g) {
#pragma unroll
        for (int s = 0; s < 8; ++s) {
            const float* p = Wh + (size_t)((g << 10) + j0 + arow) * HH
                               + ((wv << 8) + (s << 5) + (kg << 3));
            split8(p, ahh[g][s], ahl[g][s]);
        }
#pragma unroll
        for (int s = 0; s < 2; ++s) {
            const float* p = Wx + (size_t)((g << 10) + j0 + arow) * KIN
                               + ((wv << 6) + (s << 5) + (kg << 3));
            split8(p, axh[g][s], axl[g][s]);
        }
    }

    const int jh  = tid & 15;       // owned j (consecutive tid -> consecutive j)
    const int bhi = tid >> 4;       // owned b
    const int j   = j0 + jh;
    const float bxr = bx[j], bxi = bx[HH + j], bxn = bx[2 * HH + j];
    const float bhr = bh[j], bhii = bh[HH + j], bhn = bh[2 * HH + j];
    float hprev = 0.f;

    for (int t = 0; t < TT; ++t) {
        const unsigned* hs = (t & 1) ? hb1 : hb0;
        unsigned*       hd = (t & 1) ? hb0 : hb1;
        const _Float16* xs = xf + (size_t)t * (BB * KIN);

        // ---- stage h: poll packed u32 pairs until epoch >= t ----
        // 16 rows x 512 u64-chunks; 32 chunks/thread.
        unsigned long long d[32];
        unsigned pend = 0xffffffffu;
        const unsigned tgt = (unsigned)t;
        do {
            unsigned m = pend;
#pragma unroll
            for (int i = 0; i < 32; ++i) {
                if ((m >> i) & 1) {
                    int c = tid + (i << 8);
                    d[i] = ld_ag64(hs + (size_t)(b0 + (c >> 9)) * HH
                                      + ((c & 511) << 1));
                }
            }
            unsigned np = 0;
#pragma unroll
            for (int i = 0; i < 32; ++i) {
                if ((m >> i) & 1) {
                    unsigned e0 = (unsigned)(d[i] >> 16) & 0xffffu;
                    unsigned e1 = (unsigned)(d[i] >> 48);
                    if (e0 < tgt || e1 < tgt) np |= (1u << i);
                }
            }
            pend = np;
        } while (pend);
#pragma unroll
        for (int i = 0; i < 32; ++i) {
            int c = tid + (i << 8);
            int br = c >> 9, pc = c & 511;
            unsigned w = ((unsigned)(d[i] & 0xffffu))
                       | (((unsigned)((d[i] >> 32) & 0xffffu)) << 16);
            *(unsigned*)((char*)h_lds + (br << 11)
                + ((pc << 2) ^ ((br & 7) << 4))) = w;
        }

        // ---- stage x tile (plain loads; 64 blocks/group share -> L2 hits) ----
#pragma unroll
        for (int i = 0; i < 2; ++i) {
            int c = tid + (i << 8);
            int br = c >> 5, kc = c & 31;
            uint4v v = *(const uint4v*)(xs + (size_t)(b0 + br) * KIN + (kc << 3));
            *(uint4v*)((char*)x_lds + (br << 9) + ((kc << 4) ^ ((br & 7) << 4))) = v;
        }
        __syncthreads();

        // ---- MFMA: gates = W * [h; x] (hi/lo) ----
        float4v ar = {0,0,0,0}, ai = {0,0,0,0}, anx = {0,0,0,0}, anh = {0,0,0,0};
#pragma unroll
        for (int s = 0; s < 8; ++s) {
            half8 bf = *(const half8*)((char*)h_lds + (arow << 11)
                        + (((wv << 9) + (s << 6) + (kg << 4)) ^ swz));
            ar  = __builtin_amdgcn_mfma_f32_16x16x32_f16(ahh[0][s], bf, ar, 0, 0, 0);
            ar  = __builtin_amdgcn_mfma_f32_16x16x32_f16(ahl[0][s], bf, ar, 0, 0, 0);
            ai  = __builtin_amdgcn_mfma_f32_16x16x32_f16(ahh[1][s], bf, ai, 0, 0, 0);
            ai  = __builtin_amdgcn_mfma_f32_16x16x32_f16(ahl[1][s], bf, ai, 0, 0, 0);
            anh = __builtin_amdgcn_mfma_f32_16x16x32_f16(ahh[2][s], bf, anh, 0, 0, 0);
            anh = __builtin_amdgcn_mfma_f32_16x16x32_f16(ahl[2][s], bf, anh, 0, 0, 0);
        }
#pragma unroll
        for (int s = 0; s < 2; ++s) {
            half8 bf = *(const half8*)((char*)x_lds + (arow << 9)
                        + (((wv << 7) + (s << 6) + (kg << 4)) ^ swz));
            ar  = __builtin_amdgcn_mfma_f32_16x16x32_f16(axh[0][s], bf, ar, 0, 0, 0);
            ar  = __builtin_amdgcn_mfma_f32_16x16x32_f16(axl[0][s], bf, ar, 0, 0, 0);
            ai  = __builtin_amdgcn_mfma_f32_16x16x32_f16(axh[1][s], bf, ai, 0, 0, 0);
            ai  = __builtin_amdgcn_mfma_f32_16x16x32_f16(axl[1][s], bf, ai, 0, 0, 0);
            anx = __builtin_amdgcn_mfma_f32_16x16x32_f16(axh[2][s], bf, anx, 0, 0, 0);
            anx = __builtin_amdgcn_mfma_f32_16x16x32_f16(axl[2][s], bf, anx, 0, 0, 0);
        }

        // ---- cross-wave K reduction ----
#pragma unroll
        for (int r = 0; r < 4; ++r) {
            int row = (kg << 2) + r;
            red[(((wv << 2) + 0) * 16 + row) * 17 + arow] = ar[r];
            red[(((wv << 2) + 1) * 16 + row) * 17 + arow] = ai[r];
            red[(((wv << 2) + 2) * 16 + row) * 17 + arow] = anx[r];
            red[(((wv << 2) + 3) * 16 + row) * 17 + arow] = anh[r];
        }
        __syncthreads();

        float sr = 0.f, si = 0.f, sx = 0.f, sh = 0.f;
#pragma unroll
        for (int w2 = 0; w2 < 4; ++w2) {
            sr += red[(((w2 << 2) + 0) * 16 + jh) * 17 + bhi];
            si += red[(((w2 << 2) + 1) * 16 + jh) * 17 + bhi];
            sx += red[(((w2 << 2) + 2) * 16 + jh) * 17 + bhi];
            sh += red[(((w2 << 2) + 3) * 16 + jh) * 17 + bhi];
        }
        float rg = 1.f / (1.f + __expf(-(sr + bxr + bhr)));
        float ig = 1.f / (1.f + __expf(-(si + bxi + bhii)));
        float ng = tanhf(sx + bxn + rg * (sh + bhn));
        hprev = ng + ig * (hprev - ng);

        // ---- publish {tag|h} pair (jh, jh^1) as one 8B agent store ----
        unsigned short hb16;
        { union { _Float16 f; unsigned short u; } cv; cv.f = (_Float16)hprev; hb16 = cv.u; }
        unsigned myw = (((unsigned)(t + 1)) << 16) | (unsigned)hb16;
        unsigned other = (unsigned)__shfl_xor((int)myw, 1, 64);
        if ((jh & 1) == 0) {
            unsigned long long pv = (unsigned long long)myw
                                  | ((unsigned long long)other << 32);
            st_ag64(hd + (size_t)(b0 + bhi) * HH + j, pv);
        }
        // no barrier: data-as-flag epochs carry the synchronization
    }

    // ---- FC: blocks 0..63 compute out[b][:] from final h (tag 512, hb0) ----
    if (blockIdx.x < 64) {
        __syncthreads();                 // smem reuse below
        const int b = blockIdx.x;
        const unsigned* hlast = hb0;     // t=511 -> hd = hb0
        const unsigned ftgt = (unsigned)TT;
        unsigned long long e0, e1;
        do { e0 = ld_ag64(hlast + (size_t)b * HH + (tid << 2)); }
        while (((unsigned)(e0 >> 16) & 0xffffu) < ftgt || (unsigned)(e0 >> 48) < ftgt);
        do { e1 = ld_ag64(hlast + (size_t)b * HH + (tid << 2) + 2); }
        while (((unsigned)(e1 >> 16) & 0xffffu) < ftgt || (unsigned)(e1 >> 48) < ftgt);

        float hv[4];
        { union { unsigned short u; _Float16 f; } cv;
          cv.u = (unsigned short)(e0 & 0xffffu);         hv[0] = (float)cv.f;
          cv.u = (unsigned short)((e0 >> 32) & 0xffffu); hv[1] = (float)cv.f;
          cv.u = (unsigned short)(e1 & 0xffffu);         hv[2] = (float)cv.f;
          cv.u = (unsigned short)((e1 >> 32) & 0xffffu); hv[3] = (float)cv.f; }

        float partial[10];
#pragma unroll
        for (int o = 0; o < 10; ++o) {
            float4v w4 = *(const float4v*)(Wfc + (size_t)o * HH + (tid << 2));
            partial[o] = hv[0]*w4[0] + hv[1]*w4[1] + hv[2]*w4[2] + hv[3]*w4[3];
        }
        float* r = (float*)smem;   // [10][256]
#pragma unroll
        for (int o = 0; o < 10; ++o) r[o * 256 + tid] = partial[o];
        __syncthreads();
        for (int off = 128; off >= 1; off >>= 1) {
            if (tid < off) {
#pragma unroll
                for (int o = 0; o < 10; ++o)
                    r[o * 256 + tid] += r[o * 256 + tid + off];
            }
            __syncthreads();
        }
        if (tid < 10) out[b * 10 + tid] = r[tid * 256] + bfc[tid];
    }
}

extern "C" void kernel_launch(void* const* d_in, const int* in_sizes, int n_in,
                              void* d_out, int out_size, void* d_ws, size_t ws_size,
                              hipStream_t stream) {
    (void)in_sizes; (void)n_in; (void)out_size; (void)ws_size;
    const float* x   = (const float*)d_in[0];
    const float* Wx  = (const float*)d_in[1];
    const float* bx  = (const float*)d_in[2];
    const float* Wh  = (const float*)d_in[3];
    const float* bh  = (const float*)d_in[4];
    const float* Wfc = (const float*)d_in[5];
    const float* bfc = (const float*)d_in[6];
    float* out = (float*)d_out;

    char* ws = (char*)d_ws;
    _Float16* xf  = (_Float16*)(ws + XF_OFF);
    unsigned* hb0 = (unsigned*)(ws + HB0_OFF);
    unsigned* hb1 = (unsigned*)(ws + HB1_OFF);

    // reset BOTH packed h buffers every call (tags must restart at 0;
    // harness replays without re-poisoning)
    hipMemsetAsync(ws + HB0_OFF, 0, 524288, stream);

    k_prep_x<<<512, 256, 0, stream>>>(x, xf);
    k_gru_persist<<<256, 256, 0, stream>>>(xf, Wx, bx, Wh, bh, Wfc, bfc,
                                           hb0, hb1, out);
}